// Round 17
// baseline (124.797 us; speedup 1.0000x reference)
//
#include <hip/hip_runtime.h>
#include <cstdint>
#include <cstddef>

// NOBlock: B=4, N=2048, V=1, M=64 (8x8), C=128, rank 8, GRP=4.
//
// ALGEBRA: op is linear in x; mask only sets divisor w:
//   out = winv * (Tucker(sum_j x_j) + sum_j x_j)   -> one transform per GROUP.
//
// ROUND 17: break the 2-blocks/CU phase lockstep (r15/r16 showed traffic is
// NOT the binding constraint; per-CU phase serialization is). 1024 blocks x
// 512 thr, 2 groups/block: grid/CU = 4, resident 3 (LDS 47.7 KB, VGPR<=85 via
// launch_bounds(512,6)) -> 24 waves/CU and de-phased blocks so one block's
// stage-C L2 stream overlaps another's phase-A HBM stream. Full 16-load MLP
// kept (r15 proved it matters); residual via bf16 ws round-trip (frees 32
// VGPR - r15/16 proved the 67 MB doesn't matter). t1/t2 alias z2 (one fewer
// barrier per group); stage C unrolled x4 (8 FMA chains).

__device__ __forceinline__ float dot4(const float4 a, const float4 b, float s) {
    return fmaf(a.w, b.w, fmaf(a.z, b.z, fmaf(a.y, b.y, fmaf(a.x, b.x, s))));
}

__device__ __forceinline__ unsigned f2bf_pk(float lo, float hi) {
    // round-to-nearest-even bf16 pair packed into one uint
    unsigned ul = __float_as_uint(lo), uh = __float_as_uint(hi);
    ul += 0x7FFFu + ((ul >> 16) & 1u);
    uh += 0x7FFFu + ((uh >> 16) & 1u);
    return (ul >> 16) | (uh & 0xFFFF0000u);
}

// core[r][k] (512x512) -> cT[k>>2][r] as float4 over k&3. Coalesced stores.
__global__ void transpose_core(const float* __restrict__ core,
                               float* __restrict__ coreT) {
    const int tid = blockIdx.x * 256 + threadIdx.x;   // 0..65535
    const int r = tid & 511, k4 = tid >> 9;
    ((float4*)coreT)[(size_t)k4 * 512 + r] =
        ((const float4*)core)[(size_t)r * 128 + k4];
}

// ---- fused main kernel: 1024 blocks x 512 threads, 2 groups per block ----
__launch_bounds__(512, 6)
__global__ void noblock_main(const float* __restrict__ x,
                             const float* __restrict__ coreT,
                             const float* __restrict__ of0,
                             const float* __restrict__ of1,
                             const float* __restrict__ of2,
                             const float* __restrict__ if0,
                             const float* __restrict__ if1,
                             const float* __restrict__ if2,
                             const int* __restrict__ mask,
                             unsigned* __restrict__ xsum_bf,   // ws bf16 residual
                             float* __restrict__ out)
{
    __shared__ float xs[64 * 132];      // 33.8 KB xsum tile (reused per group)
    __shared__ float zz[1024];          // 2 groups' z; dead after C -> t1d
    __shared__ float z2[1024];          // t1/t2 alias in phase A; C out; -> t2d
    __shared__ float s_if2T[8 * 132];   // [F][e], padded
    __shared__ float s_if0[64], s_if1[64];
    __shared__ float s_of0T[64], s_of1T[64];   // [A][o], [B][p]
    __shared__ float s_winv[128];       // [g][m]
    float* t1 = z2;                     // z2 dead during phase A
    float* t2 = z2 + 512;
    float* t1d = zz;                    // zz dead after stage C
    float* t2d = z2;                    // z2(C-out) dead after D1

    const int t = threadIdx.x;          // 0..511
    const size_t g0 = (size_t)blockIdx.x * 2;

    // ---- staging: factors (if2 transposed), winv ----
    for (int i = t; i < 1024; i += 512) {
        const int e = i & 127, F = i >> 7;
        s_if2T[F * 132 + e] = if2[e * 8 + F];
    }
    if (t < 64) {
        s_if0[t] = if0[t];
        s_if1[t] = if1[t];
        s_of0T[t] = of0[(t & 7) * 8 + (t >> 3)];
        s_of1T[t] = of1[(t & 7) * 8 + (t >> 3)];
    }
    if (t < 128) {
        const int g = t >> 6, m = t & 63;
        const int* mp = mask + (g0 + g) * 4 * 64 + m;
        int cnt = 0;
        #pragma unroll
        for (int j = 0; j < 4; ++j) cnt += (mp[j * 64] == 0) ? 1 : 0;
        s_winv[t] = cnt ? 1.0f / (float)cnt : 0.0f;
    }
    // first __syncthreads below (group 0) covers staging

    // ---- phase A: per group, xsum + in-projection -> zz (LDS) ----
    #pragma unroll 1
    for (int g = 0; g < 2; ++g) {
        const float4* xg4 = (const float4*)x + (g0 + g) * 8192;  // 4 tokens
        // all 16 loads issued up-front for max MLP
        float4 v[4][4];
        #pragma unroll
        for (int j = 0; j < 4; ++j)
            #pragma unroll
            for (int i = 0; i < 4; ++i)
                v[j][i] = xg4[(size_t)j * 2048 + t + 512 * i];
        float4 acc[4];
        #pragma unroll
        for (int i = 0; i < 4; ++i) {
            acc[i].x = (v[0][i].x + v[1][i].x) + (v[2][i].x + v[3][i].x);
            acc[i].y = (v[0][i].y + v[1][i].y) + (v[2][i].y + v[3][i].y);
            acc[i].z = (v[0][i].z + v[1][i].z) + (v[2][i].z + v[3][i].z);
            acc[i].w = (v[0][i].w + v[1][i].w) + (v[2][i].w + v[3][i].w);
        }
        // bf16 residual -> ws (coalesced uint2 = 4 values / thread / i)
        uint2* xo = (uint2*)xsum_bf + (g0 + g) * 2048;
        #pragma unroll
        for (int i = 0; i < 4; ++i) {
            uint2 pk;
            pk.x = f2bf_pk(acc[i].x, acc[i].y);
            pk.y = f2bf_pk(acc[i].z, acc[i].w);
            xo[t + 512 * i] = pk;
        }
        // padded LDS tile
        #pragma unroll
        for (int i = 0; i < 4; ++i) {
            const int f4i = t + 512 * i;
            *(float4*)&xs[(f4i >> 5) * 132 + (f4i & 31) * 4] = acc[i];
        }
        __syncthreads();   // xs ready (g=0: also staging ready)

        // stage A: one output/thread: t1[t] = sum_e xs[m][e] * if2T[F][e]
        {
            const int m = t >> 3, F = t & 7;
            const float4* xrp = (const float4*)(xs + m * 132);
            const float4* wr = (const float4*)(s_if2T + F * 132);
            float s0 = 0.f, s1 = 0.f;
            #pragma unroll
            for (int e4 = 0; e4 < 32; e4 += 2) {
                s0 = dot4(xrp[e4],     wr[e4],     s0);
                s1 = dot4(xrp[e4 + 1], wr[e4 + 1], s1);
            }
            t1[t] = s0 + s1;   // t1 aliases z2 (not xs) -> direct write OK
        }
        __syncthreads();   // t1 ready (and all xs reads done)

        // B1: t2[E*64+a*8+F] = sum_d t1[a*64+d*8+F] * if1[d][E]
        {
            const int E = t >> 6, a = (t >> 3) & 7, F = t & 7;
            float s = 0.f;
            #pragma unroll
            for (int d0 = 0; d0 < 8; ++d0) {
                const int d = (d0 + a) & 7;           // stagger: 2-way banks
                s = fmaf(t1[a * 64 + d * 8 + F], s_if1[d * 8 + E], s);
            }
            t2[t] = s;
        }
        __syncthreads();   // t2 ready

        // B2: zz[g*512 + D*64+E*8+F] = sum_a t2[E*64+a*8+F] * if0[a][D]
        {
            const int D = t >> 6, E = (t >> 3) & 7, F = t & 7;
            float s = 0.f;
            #pragma unroll
            for (int a0 = 0; a0 < 8; ++a0) {
                const int a = (a0 + E) & 7;           // stagger: 2-way banks
                s = fmaf(t2[E * 64 + a * 8 + F], s_if0[a * 8 + D], s);
            }
            zz[g * 512 + t] = s;
        }
        // no barrier needed here: next group's xs/t1 writes are ordered by
        // the barriers above; zz[g] is read only after the barrier below
    }
    __syncthreads();   // zz complete; z2 (t1/t2) dead -> stage C may overwrite

    // ---- stage C: z2[g][r] = sum_k coreT[k][r] * zz[g][k]; 1 row/thread,
    // coalesced L2 stream, 8 independent FMA chains (2 groups x 4-deep k4)
    {
        const float4* cT = (const float4*)coreT;
        const float4* z4 = (const float4*)zz;
        float a0[2] = {0, 0}, a1[2] = {0, 0}, a2[2] = {0, 0}, a3[2] = {0, 0};
        for (int k4 = 0; k4 < 128; k4 += 4) {
            const float4 c0 = cT[(size_t)(k4 + 0) * 512 + t];
            const float4 c1 = cT[(size_t)(k4 + 1) * 512 + t];
            const float4 c2 = cT[(size_t)(k4 + 2) * 512 + t];
            const float4 c3 = cT[(size_t)(k4 + 3) * 512 + t];
            #pragma unroll
            for (int g = 0; g < 2; ++g) {
                a0[g] = dot4(c0, z4[g * 128 + k4 + 0], a0[g]);   // LDS broadcast
                a1[g] = dot4(c1, z4[g * 128 + k4 + 1], a1[g]);
                a2[g] = dot4(c2, z4[g * 128 + k4 + 2], a2[g]);
                a3[g] = dot4(c3, z4[g * 128 + k4 + 3], a3[g]);
            }
        }
        #pragma unroll
        for (int g = 0; g < 2; ++g)
            z2[g * 512 + t] = (a0[g] + a1[g]) + (a2[g] + a3[g]);
    }
    __syncthreads();   // zz dead from here

    // ---- D1 (batched): t1d[g][o*64+Bq*8+Cr] = sum_A z2[g][..] * of0T[A][o] ----
    #pragma unroll
    for (int h = 0; h < 2; ++h) {
        const int id2 = t + 512 * h;
        const int g = id2 >> 9, rem = id2 & 511;
        const int o = rem >> 6, Bq = (rem >> 3) & 7, Cr = rem & 7;
        float s = 0.f;
        #pragma unroll
        for (int A = 0; A < 8; ++A)
            s = fmaf(z2[g * 512 + A * 64 + Bq * 8 + Cr], s_of0T[A * 8 + o], s);
        t1d[id2] = s;
    }
    __syncthreads();   // z2 dead from here

    // ---- D2 (batched): t2d[g][p*64+o*8+Cr] = sum_B t1d[g][..] * of1T[B][p] ----
    #pragma unroll
    for (int h = 0; h < 2; ++h) {
        const int id2 = t + 512 * h;
        const int g = id2 >> 9, rem = id2 & 511;
        const int p = rem >> 6, o = (rem >> 3) & 7, Cr = rem & 7;
        float s = 0.f;
        #pragma unroll
        for (int B0 = 0; B0 < 8; ++B0) {
            const int Bq = (B0 + o) & 7;              // stagger: 2-way banks
            s = fmaf(t1d[g * 512 + o * 64 + Bq * 8 + Cr], s_of1T[Bq * 8 + p], s);
        }
        t2d[id2] = s;
    }
    __syncthreads();

    // ---- D3: h = v.of2 + bf16(xsum), *winv, write d_out (write-once) ----
    float4 w[4][2];
    {
        const int cc = (4 * t) & 127;
        #pragma unroll
        for (int c = 0; c < 4; ++c) {
            w[c][0] = *(const float4*)(of2 + (cc + c) * 8);
            w[c][1] = *(const float4*)(of2 + (cc + c) * 8 + 4);
        }
    }
    float4* out4 = (float4*)out;
    #pragma unroll
    for (int g = 0; g < 2; ++g) {
        const size_t obase = (g0 + g) * 2048;
        const uint2* xb = (const uint2*)xsum_bf + obase;
        uint2 xp[4];
        #pragma unroll
        for (int i = 0; i < 4; ++i) xp[i] = xb[t + 512 * i];
        #pragma unroll
        for (int i = 0; i < 4; ++i) {
            const int m = (t >> 5) + 16 * i;
            const int o = m >> 3, p = m & 7;
            const float wv = s_winv[g * 64 + m];
            const int base = g * 512 + p * 64 + o * 8;
            const float4 v0 = *(const float4*)(t2d + base);   // broadcast
            const float4 v1 = *(const float4*)(t2d + base + 4);
            const float rx = __uint_as_float(xp[i].x << 16);
            const float ry = __uint_as_float(xp[i].x & 0xFFFF0000u);
            const float rz = __uint_as_float(xp[i].y << 16);
            const float rw = __uint_as_float(xp[i].y & 0xFFFF0000u);
            float4 r;
            r.x = dot4(v1, w[0][1], dot4(v0, w[0][0], rx));
            r.y = dot4(v1, w[1][1], dot4(v0, w[1][0], ry));
            r.z = dot4(v1, w[2][1], dot4(v0, w[2][0], rz));
            r.w = dot4(v1, w[3][1], dot4(v0, w[3][0], rw));
            r.x *= wv; r.y *= wv; r.z *= wv; r.w *= wv;
            out4[obase + t + 512 * i] = r;
        }
    }
}

// ================= fallback (no ws): single fused kernel, strided core ======
__launch_bounds__(256, 3)
__global__ void noblock_fused(const float* __restrict__ x,
                              const float* __restrict__ core,
                              const float* __restrict__ of0,
                              const float* __restrict__ of1,
                              const float* __restrict__ of2,
                              const float* __restrict__ if0,
                              const float* __restrict__ if1,
                              const float* __restrict__ if2,
                              const int* __restrict__ mask,
                              float* __restrict__ out)
{
    __shared__ float xs[64 * 132];
    __shared__ float t1[512];
    __shared__ float t2[512];
    __shared__ float zz[2 * 512];
    __shared__ float z2[2 * 512];
    __shared__ float s_if2T[8 * 132];
    __shared__ float s_if0[64], s_if1[64];
    __shared__ float s_of0T[64], s_of1T[64];
    __shared__ float s_winv[128];

    const int t = threadIdx.x;
    const int blk = blockIdx.x;

    for (int i = t; i < 1024; i += 256) {
        const int e = i & 127, F = i >> 7;
        s_if2T[F * 132 + e] = if2[e * 8 + F];
    }
    if (t < 64) {
        s_if0[t] = if0[t];
        s_if1[t] = if1[t];
        s_of0T[t] = of0[(t & 7) * 8 + (t >> 3)];
        s_of1T[t] = of1[(t & 7) * 8 + (t >> 3)];
    }
    if (t < 128) {
        const int g = t >> 6, mm = t & 63;
        const int* mp = mask + ((size_t)(blk * 2 + g) * 4) * 64 + mm;
        int cnt = 0;
        #pragma unroll
        for (int j = 0; j < 4; ++j) cnt += (mp[j * 64] == 0) ? 1 : 0;
        s_winv[t] = cnt ? 1.0f / (float)cnt : 0.0f;
    }

    float4 acc[2][8];
    const float4* xg4 = (const float4*)(x + (size_t)blk * 8 * 8192);
    #pragma unroll
    for (int g = 0; g < 2; ++g)
        #pragma unroll
        for (int i = 0; i < 8; ++i)
            acc[g][i] = xg4[(size_t)(g * 4) * 2048 + t + 256 * i];
    #pragma unroll
    for (int j = 1; j < 4; ++j) {
        #pragma unroll
        for (int g = 0; g < 2; ++g) {
            float4 v[8];
            #pragma unroll
            for (int i = 0; i < 8; ++i)
                v[i] = xg4[(size_t)(g * 4 + j) * 2048 + t + 256 * i];
            #pragma unroll
            for (int i = 0; i < 8; ++i) {
                acc[g][i].x += v[i].x; acc[g][i].y += v[i].y;
                acc[g][i].z += v[i].z; acc[g][i].w += v[i].w;
            }
        }
    }

    #pragma unroll
    for (int g = 0; g < 2; ++g) {
        #pragma unroll
        for (int i = 0; i < 8; ++i) {
            const int f4i = t + 256 * i;
            *(float4*)&xs[(f4i >> 5) * 132 + (f4i & 31) * 4] = acc[g][i];
        }
        __syncthreads();
        #pragma unroll
        for (int h = 0; h < 2; ++h) {
            const int id = t + 256 * h;
            const int m = id >> 3, F = id & 7;
            const float4* xr = (const float4*)(xs + m * 132);
            const float4* wr = (const float4*)(s_if2T + F * 132);
            float s0 = 0.f, s1 = 0.f;
            #pragma unroll
            for (int e4 = 0; e4 < 32; e4 += 2) {
                s0 = dot4(xr[e4],     wr[e4],     s0);
                s1 = dot4(xr[e4 + 1], wr[e4 + 1], s1);
            }
            t1[id] = s0 + s1;
        }
        __syncthreads();
        #pragma unroll
        for (int h = 0; h < 2; ++h) {
            const int id = t + 256 * h;
            const int E = id >> 6, a = (id >> 3) & 7, F = id & 7;
            float s = 0.f;
            #pragma unroll
            for (int d0 = 0; d0 < 8; ++d0) {
                const int d = (d0 + a) & 7;
                s = fmaf(t1[a * 64 + d * 8 + F], s_if1[d * 8 + E], s);
            }
            t2[id] = s;
        }
        __syncthreads();
        #pragma unroll
        for (int h = 0; h < 2; ++h) {
            const int id = t + 256 * h;
            const int D = id >> 6, E = (id >> 3) & 7, F = id & 7;
            float s = 0.f;
            #pragma unroll
            for (int a0 = 0; a0 < 8; ++a0) {
                const int a = (a0 + E) & 7;
                s = fmaf(t2[E * 64 + a * 8 + F], s_if0[a * 8 + D], s);
            }
            zz[g * 512 + id] = s;
        }
        __syncthreads();
    }

    {
        const float4* cr0 = (const float4*)(core + (size_t)t * 512);
        const float4* cr1 = (const float4*)(core + (size_t)(t + 256) * 512);
        const float4* z4 = (const float4*)zz;
        float a0[2] = {0.f, 0.f}, a1[2] = {0.f, 0.f};
        for (int kk = 0; kk < 128; ++kk) {
            const float4 c0 = cr0[kk], c1 = cr1[kk];
            #pragma unroll
            for (int g = 0; g < 2; ++g) {
                const float4 zv = z4[g * 128 + kk];
                a0[g] = dot4(c0, zv, a0[g]);
                a1[g] = dot4(c1, zv, a1[g]);
            }
        }
        #pragma unroll
        for (int g = 0; g < 2; ++g) {
            z2[g * 512 + t]       = a0[g];
            z2[g * 512 + t + 256] = a1[g];
        }
    }
    __syncthreads();

    float4 w[4][2];
    {
        const int cc = (4 * t) & 127;
        #pragma unroll
        for (int c = 0; c < 4; ++c) {
            w[c][0] = *(const float4*)(of2 + (cc + c) * 8);
            w[c][1] = *(const float4*)(of2 + (cc + c) * 8 + 4);
        }
    }

    float4* out4 = (float4*)out;
    #pragma unroll
    for (int g = 0; g < 2; ++g) {
        #pragma unroll
        for (int h = 0; h < 2; ++h) {
            const int id = t + 256 * h;
            const int o = id >> 6, Bq = (id >> 3) & 7, Cr = id & 7;
            float s = 0.f;
            #pragma unroll
            for (int A = 0; A < 8; ++A)
                s = fmaf(z2[g * 512 + A * 64 + Bq * 8 + Cr], s_of0T[A * 8 + o], s);
            t1[id] = s;
        }
        __syncthreads();
        #pragma unroll
        for (int h = 0; h < 2; ++h) {
            const int id = t + 256 * h;
            const int p = id >> 6, o = (id >> 3) & 7, Cr = id & 7;
            float s = 0.f;
            #pragma unroll
            for (int B0 = 0; B0 < 8; ++B0) {
                const int Bq = (B0 + o) & 7;
                s = fmaf(t1[o * 64 + Bq * 8 + Cr], s_of1T[Bq * 8 + p], s);
            }
            t2[id] = s;
        }
        __syncthreads();
        #pragma unroll
        for (int i = 0; i < 8; ++i) {
            const int m = (t >> 5) + 8 * i;
            const int o = m >> 3, p = m & 7;
            const float wv = s_winv[g * 64 + m];
            const int base = p * 64 + o * 8;
            const float4 v0 = *(const float4*)(t2 + base);
            const float4 v1 = *(const float4*)(t2 + base + 4);
            float4 r;
            r.x = dot4(v1, w[0][1], dot4(v0, w[0][0], acc[g][i].x));
            r.y = dot4(v1, w[1][1], dot4(v0, w[1][0], acc[g][i].y));
            r.z = dot4(v1, w[2][1], dot4(v0, w[2][0], acc[g][i].z));
            r.w = dot4(v1, w[3][1], dot4(v0, w[3][0], acc[g][i].w));
            r.x *= wv; r.y *= wv; r.z *= wv; r.w *= wv;
            out4[(size_t)(blk * 2 + g) * 2048 + t + 256 * i] = r;
        }
        __syncthreads();
    }
}

extern "C" void kernel_launch(void* const* d_in, const int* in_sizes, int n_in,
                              void* d_out, int out_size, void* d_ws, size_t ws_size,
                              hipStream_t stream) {
    const float* x    = (const float*)d_in[0];
    const float* core = (const float*)d_in[1];
    const float* of0  = (const float*)d_in[2];
    const float* of1  = (const float*)d_in[3];
    const float* of2  = (const float*)d_in[4];
    const float* if0  = (const float*)d_in[5];
    const float* if1  = (const float*)d_in[6];
    const float* if2  = (const float*)d_in[7];
    const int* mask   = (const int*)d_in[8];
    float* out = (float*)d_out;

    const size_t CORE_T_BYTES = (size_t)512 * 512 * 4;            // 1 MB
    const size_t XS_BYTES     = (size_t)2048 * 8192 * 2;          // 33.5 MB bf16

    if (d_ws && ws_size >= CORE_T_BYTES + XS_BYTES) {
        float* coreT    = (float*)d_ws;
        unsigned* xs_bf = (unsigned*)((char*)d_ws + CORE_T_BYTES);
        transpose_core<<<dim3(256), dim3(256), 0, stream>>>(core, coreT);
        noblock_main<<<dim3(1024), dim3(512), 0, stream>>>(
            x, coreT, of0, of1, of2, if0, if1, if2, mask, xs_bf, out);
    } else {
        noblock_fused<<<dim3(1024), dim3(256), 0, stream>>>(
            x, core, of0, of1, of2, if0, if1, if2, mask, out);
    }
}

// Round 18
// 106.544 us; speedup vs baseline: 1.1713x; 1.1713x over previous
//
#include <hip/hip_runtime.h>
#include <cstdint>
#include <cstddef>

// NOBlock: B=4, N=2048, V=1, M=64 (8x8), C=128, rank 8, GRP=4.
//
// ALGEBRA: op is linear in x; mask only sets divisor w:
//   out = winv * (Tucker(sum_j x_j) + sum_j x_j)   -> one transform per GROUP.
//
// ROUND 18: revert to r14 (best: 107.6 us) + one barrier saving from r17:
// t1/t2 alias z2 (not xs), so stage A writes t1 directly -> 4 fewer barriers
// per block. KEY LESSON (r15/r17): phase-A needs all 16 x-loads in flight,
// which needs ~64 VGPRs -> launch_bounds(512,2) (no VGPR clamp; r17's (512,6)
// collapsed to 40 VGPR and serialized the loads, -15%).
//   T:    core[512][512] -> coreT[k4][r] (tiny pre-launch)
//   main: 512 blocks x 512 thr, 4 groups/block, 2 blocks/CU (LDS 56.5 KB):
//         per group {xsum -> bf16 ws + LDS tile; A -> t1; B1 -> t2; B2 -> zz};
//         stage C = coreT . zz (coalesced L2 stream, 8 FMA chains);
//         D1/D2 out-proj; D3 + bf16 residual, *winv, write d_out once.

__device__ __forceinline__ float dot4(const float4 a, const float4 b, float s) {
    return fmaf(a.w, b.w, fmaf(a.z, b.z, fmaf(a.y, b.y, fmaf(a.x, b.x, s))));
}

__device__ __forceinline__ unsigned f2bf_pk(float lo, float hi) {
    // round-to-nearest-even bf16 pair packed into one uint
    unsigned ul = __float_as_uint(lo), uh = __float_as_uint(hi);
    ul += 0x7FFFu + ((ul >> 16) & 1u);
    uh += 0x7FFFu + ((uh >> 16) & 1u);
    return (ul >> 16) | (uh & 0xFFFF0000u);
}

// core[r][k] (512x512) -> cT[k>>2][r] as float4 over k&3. Coalesced stores.
__global__ void transpose_core(const float* __restrict__ core,
                               float* __restrict__ coreT) {
    const int tid = blockIdx.x * 256 + threadIdx.x;   // 0..65535
    const int r = tid & 511, k4 = tid >> 9;
    ((float4*)coreT)[(size_t)k4 * 512 + r] =
        ((const float4*)core)[(size_t)r * 128 + k4];
}

// ---- fused main kernel: 512 blocks x 512 threads, 4 groups per block ----
__launch_bounds__(512, 2)
__global__ void noblock_main(const float* __restrict__ x,
                             const float* __restrict__ coreT,
                             const float* __restrict__ of0,
                             const float* __restrict__ of1,
                             const float* __restrict__ of2,
                             const float* __restrict__ if0,
                             const float* __restrict__ if1,
                             const float* __restrict__ if2,
                             const int* __restrict__ mask,
                             unsigned* __restrict__ xsum_bf,   // ws bf16 residual
                             float* __restrict__ out)
{
    __shared__ float xs[64 * 132];      // 33.8 KB xsum tile (reused per group)
    __shared__ float zz[2048];          // 4 groups' z; dead after C -> t1d
    __shared__ float z2[2048];          // t1/t2 in phase A; C out; dead after D1 -> t2d
    __shared__ float s_if2T[8 * 132];   // [F][e], padded
    __shared__ float s_if0[64], s_if1[64];
    __shared__ float s_of0T[64], s_of1T[64];   // [A][o], [B][p]
    __shared__ float s_winv[256];       // [g][m]
    float* t1 = z2;                     // z2 dead during phase A
    float* t2 = z2 + 512;
    float* t1d = zz;                    // zz dead after stage C
    float* t2d = z2;                    // z2 (C out) dead after D1

    const int t = threadIdx.x;          // 0..511
    const size_t g0 = (size_t)blockIdx.x * 4;

    // ---- staging: factors (if2 transposed), winv ----
    for (int i = t; i < 1024; i += 512) {
        const int e = i & 127, F = i >> 7;
        s_if2T[F * 132 + e] = if2[e * 8 + F];
    }
    if (t < 64) {
        s_if0[t] = if0[t];
        s_if1[t] = if1[t];
        s_of0T[t] = of0[(t & 7) * 8 + (t >> 3)];
        s_of1T[t] = of1[(t & 7) * 8 + (t >> 3)];
    }
    if (t < 256) {
        const int g = t >> 6, m = t & 63;
        const int* mp = mask + (g0 + g) * 4 * 64 + m;
        int cnt = 0;
        #pragma unroll
        for (int j = 0; j < 4; ++j) cnt += (mp[j * 64] == 0) ? 1 : 0;
        s_winv[t] = cnt ? 1.0f / (float)cnt : 0.0f;
    }
    // first __syncthreads below (group 0) covers staging

    // ---- phase A: per group, xsum + in-projection -> zz (LDS) ----
    #pragma unroll 1
    for (int g = 0; g < 4; ++g) {
        const float4* xg4 = (const float4*)x + (g0 + g) * 8192;  // 4 tokens
        // all 16 loads issued up-front for max MLP (needs ~64 VGPR - do not clamp)
        float4 v[4][4];
        #pragma unroll
        for (int j = 0; j < 4; ++j)
            #pragma unroll
            for (int i = 0; i < 4; ++i)
                v[j][i] = xg4[(size_t)j * 2048 + t + 512 * i];
        float4 acc[4];
        #pragma unroll
        for (int i = 0; i < 4; ++i) {
            acc[i].x = (v[0][i].x + v[1][i].x) + (v[2][i].x + v[3][i].x);
            acc[i].y = (v[0][i].y + v[1][i].y) + (v[2][i].y + v[3][i].y);
            acc[i].z = (v[0][i].z + v[1][i].z) + (v[2][i].z + v[3][i].z);
            acc[i].w = (v[0][i].w + v[1][i].w) + (v[2][i].w + v[3][i].w);
        }
        // bf16 residual -> ws (coalesced uint2 = 4 values / thread / i)
        uint2* xo = (uint2*)xsum_bf + (g0 + g) * 2048;
        #pragma unroll
        for (int i = 0; i < 4; ++i) {
            uint2 pk;
            pk.x = f2bf_pk(acc[i].x, acc[i].y);
            pk.y = f2bf_pk(acc[i].z, acc[i].w);
            xo[t + 512 * i] = pk;
        }
        // padded LDS tile
        #pragma unroll
        for (int i = 0; i < 4; ++i) {
            const int f4i = t + 512 * i;
            *(float4*)&xs[(f4i >> 5) * 132 + (f4i & 31) * 4] = acc[i];
        }
        __syncthreads();   // xs ready (g=0: also staging ready)

        // stage A: t1[t] = sum_e xs[m][e] * if2T[F][e]  (t1 aliases z2, not xs
        // -> direct write, no intermediate barrier)
        {
            const int m = t >> 3, F = t & 7;
            const float4* xrp = (const float4*)(xs + m * 132);
            const float4* wr = (const float4*)(s_if2T + F * 132);
            float s0 = 0.f, s1 = 0.f;
            #pragma unroll
            for (int e4 = 0; e4 < 32; e4 += 2) {
                s0 = dot4(xrp[e4],     wr[e4],     s0);
                s1 = dot4(xrp[e4 + 1], wr[e4 + 1], s1);
            }
            t1[t] = s0 + s1;
        }
        __syncthreads();   // t1 ready (and all xs reads done)

        // B1: t2[E*64+a*8+F] = sum_d t1[a*64+d*8+F] * if1[d][E]
        {
            const int E = t >> 6, a = (t >> 3) & 7, F = t & 7;
            float s = 0.f;
            #pragma unroll
            for (int d0 = 0; d0 < 8; ++d0) {
                const int d = (d0 + a) & 7;           // stagger: 2-way banks
                s = fmaf(t1[a * 64 + d * 8 + F], s_if1[d * 8 + E], s);
            }
            t2[t] = s;
        }
        __syncthreads();   // t2 ready

        // B2: zz[g*512 + D*64+E*8+F] = sum_a t2[E*64+a*8+F] * if0[a][D]
        {
            const int D = t >> 6, E = (t >> 3) & 7, F = t & 7;
            float s = 0.f;
            #pragma unroll
            for (int a0 = 0; a0 < 8; ++a0) {
                const int a = (a0 + E) & 7;           // stagger: 2-way banks
                s = fmaf(t2[E * 64 + a * 8 + F], s_if0[a * 8 + D], s);
            }
            zz[g * 512 + t] = s;
        }
        __syncthreads();   // zz[g] ready; xs/t1/t2 reusable next group
    }

    // ---- stage C: z2[g][r] = sum_k coreT[k][r] * zz[g][k]; 1 row/thread,
    // coalesced L2 stream, 8 independent FMA chains (4 groups x even/odd k4)
    {
        const float4* cT = (const float4*)coreT;
        const float4* z4 = (const float4*)zz;
        float a0[4] = {0, 0, 0, 0}, a1[4] = {0, 0, 0, 0};
        for (int k4 = 0; k4 < 128; k4 += 2) {
            const float4 c0 = cT[(size_t)k4 * 512 + t];
            const float4 c1 = cT[(size_t)(k4 + 1) * 512 + t];
            #pragma unroll
            for (int g = 0; g < 4; ++g) {
                a0[g] = dot4(c0, z4[g * 128 + k4],     a0[g]);   // LDS broadcast
                a1[g] = dot4(c1, z4[g * 128 + k4 + 1], a1[g]);
            }
        }
        #pragma unroll
        for (int g = 0; g < 4; ++g) z2[g * 512 + t] = a0[g] + a1[g];
    }
    __syncthreads();   // zz dead from here

    // ---- D1 (batched): t1d[g][o*64+Bq*8+Cr] = sum_A z2[g][..] * of0T[A][o] ----
    #pragma unroll
    for (int h = 0; h < 4; ++h) {
        const int id2 = t + 512 * h;
        const int g = id2 >> 9, rem = id2 & 511;
        const int o = rem >> 6, Bq = (rem >> 3) & 7, Cr = rem & 7;
        float s = 0.f;
        #pragma unroll
        for (int A = 0; A < 8; ++A)
            s = fmaf(z2[g * 512 + A * 64 + Bq * 8 + Cr], s_of0T[A * 8 + o], s);
        t1d[id2] = s;
    }
    __syncthreads();   // z2 dead from here

    // ---- D2 (batched): t2d[g][p*64+o*8+Cr] = sum_B t1d[g][..] * of1T[B][p] ----
    #pragma unroll
    for (int h = 0; h < 4; ++h) {
        const int id2 = t + 512 * h;
        const int g = id2 >> 9, rem = id2 & 511;
        const int p = rem >> 6, o = (rem >> 3) & 7, Cr = rem & 7;
        float s = 0.f;
        #pragma unroll
        for (int B0 = 0; B0 < 8; ++B0) {
            const int Bq = (B0 + o) & 7;              // stagger: 2-way banks
            s = fmaf(t1d[g * 512 + o * 64 + Bq * 8 + Cr], s_of1T[Bq * 8 + p], s);
        }
        t2d[id2] = s;
    }
    __syncthreads();

    // ---- D3: h = v.of2 + bf16(xsum), *winv, write d_out (write-once) ----
    float4 w[4][2];
    {
        const int cc = (4 * t) & 127;
        #pragma unroll
        for (int c = 0; c < 4; ++c) {
            w[c][0] = *(const float4*)(of2 + (cc + c) * 8);
            w[c][1] = *(const float4*)(of2 + (cc + c) * 8 + 4);
        }
    }
    float4* out4 = (float4*)out;
    #pragma unroll
    for (int g = 0; g < 4; ++g) {
        const size_t obase = (g0 + g) * 2048;
        const uint2* xb = (const uint2*)xsum_bf + obase;
        uint2 xp[4];
        #pragma unroll
        for (int i = 0; i < 4; ++i) xp[i] = xb[t + 512 * i];
        #pragma unroll
        for (int i = 0; i < 4; ++i) {
            const int m = (t >> 5) + 16 * i;
            const int o = m >> 3, p = m & 7;
            const float wv = s_winv[g * 64 + m];
            const int base = g * 512 + p * 64 + o * 8;
            const float4 v0 = *(const float4*)(t2d + base);   // broadcast
            const float4 v1 = *(const float4*)(t2d + base + 4);
            const float rx = __uint_as_float(xp[i].x << 16);
            const float ry = __uint_as_float(xp[i].x & 0xFFFF0000u);
            const float rz = __uint_as_float(xp[i].y << 16);
            const float rw = __uint_as_float(xp[i].y & 0xFFFF0000u);
            float4 r;
            r.x = dot4(v1, w[0][1], dot4(v0, w[0][0], rx));
            r.y = dot4(v1, w[1][1], dot4(v0, w[1][0], ry));
            r.z = dot4(v1, w[2][1], dot4(v0, w[2][0], rz));
            r.w = dot4(v1, w[3][1], dot4(v0, w[3][0], rw));
            r.x *= wv; r.y *= wv; r.z *= wv; r.w *= wv;
            out4[obase + t + 512 * i] = r;
        }
    }
}

// ================= fallback (no ws): single fused kernel, strided core ======
__launch_bounds__(256, 3)
__global__ void noblock_fused(const float* __restrict__ x,
                              const float* __restrict__ core,
                              const float* __restrict__ of0,
                              const float* __restrict__ of1,
                              const float* __restrict__ of2,
                              const float* __restrict__ if0,
                              const float* __restrict__ if1,
                              const float* __restrict__ if2,
                              const int* __restrict__ mask,
                              float* __restrict__ out)
{
    __shared__ float xs[64 * 132];
    __shared__ float t1[512];
    __shared__ float t2[512];
    __shared__ float zz[2 * 512];
    __shared__ float z2[2 * 512];
    __shared__ float s_if2T[8 * 132];
    __shared__ float s_if0[64], s_if1[64];
    __shared__ float s_of0T[64], s_of1T[64];
    __shared__ float s_winv[128];

    const int t = threadIdx.x;
    const int blk = blockIdx.x;

    for (int i = t; i < 1024; i += 256) {
        const int e = i & 127, F = i >> 7;
        s_if2T[F * 132 + e] = if2[e * 8 + F];
    }
    if (t < 64) {
        s_if0[t] = if0[t];
        s_if1[t] = if1[t];
        s_of0T[t] = of0[(t & 7) * 8 + (t >> 3)];
        s_of1T[t] = of1[(t & 7) * 8 + (t >> 3)];
    }
    if (t < 128) {
        const int g = t >> 6, mm = t & 63;
        const int* mp = mask + ((size_t)(blk * 2 + g) * 4) * 64 + mm;
        int cnt = 0;
        #pragma unroll
        for (int j = 0; j < 4; ++j) cnt += (mp[j * 64] == 0) ? 1 : 0;
        s_winv[t] = cnt ? 1.0f / (float)cnt : 0.0f;
    }

    float4 acc[2][8];
    const float4* xg4 = (const float4*)(x + (size_t)blk * 8 * 8192);
    #pragma unroll
    for (int g = 0; g < 2; ++g)
        #pragma unroll
        for (int i = 0; i < 8; ++i)
            acc[g][i] = xg4[(size_t)(g * 4) * 2048 + t + 256 * i];
    #pragma unroll
    for (int j = 1; j < 4; ++j) {
        #pragma unroll
        for (int g = 0; g < 2; ++g) {
            float4 v[8];
            #pragma unroll
            for (int i = 0; i < 8; ++i)
                v[i] = xg4[(size_t)(g * 4 + j) * 2048 + t + 256 * i];
            #pragma unroll
            for (int i = 0; i < 8; ++i) {
                acc[g][i].x += v[i].x; acc[g][i].y += v[i].y;
                acc[g][i].z += v[i].z; acc[g][i].w += v[i].w;
            }
        }
    }

    #pragma unroll
    for (int g = 0; g < 2; ++g) {
        #pragma unroll
        for (int i = 0; i < 8; ++i) {
            const int f4i = t + 256 * i;
            *(float4*)&xs[(f4i >> 5) * 132 + (f4i & 31) * 4] = acc[g][i];
        }
        __syncthreads();
        #pragma unroll
        for (int h = 0; h < 2; ++h) {
            const int id = t + 256 * h;
            const int m = id >> 3, F = id & 7;
            const float4* xr = (const float4*)(xs + m * 132);
            const float4* wr = (const float4*)(s_if2T + F * 132);
            float s0 = 0.f, s1 = 0.f;
            #pragma unroll
            for (int e4 = 0; e4 < 32; e4 += 2) {
                s0 = dot4(xr[e4],     wr[e4],     s0);
                s1 = dot4(xr[e4 + 1], wr[e4 + 1], s1);
            }
            t1[id] = s0 + s1;
        }
        __syncthreads();
        #pragma unroll
        for (int h = 0; h < 2; ++h) {
            const int id = t + 256 * h;
            const int E = id >> 6, a = (id >> 3) & 7, F = id & 7;
            float s = 0.f;
            #pragma unroll
            for (int d0 = 0; d0 < 8; ++d0) {
                const int d = (d0 + a) & 7;
                s = fmaf(t1[a * 64 + d * 8 + F], s_if1[d * 8 + E], s);
            }
            t2[id] = s;
        }
        __syncthreads();
        #pragma unroll
        for (int h = 0; h < 2; ++h) {
            const int id = t + 256 * h;
            const int D = id >> 6, E = (id >> 3) & 7, F = id & 7;
            float s = 0.f;
            #pragma unroll
            for (int a0 = 0; a0 < 8; ++a0) {
                const int a = (a0 + E) & 7;
                s = fmaf(t2[E * 64 + a * 8 + F], s_if0[a * 8 + D], s);
            }
            zz[g * 512 + id] = s;
        }
        __syncthreads();
    }

    {
        const float4* cr0 = (const float4*)(core + (size_t)t * 512);
        const float4* cr1 = (const float4*)(core + (size_t)(t + 256) * 512);
        const float4* z4 = (const float4*)zz;
        float a0[2] = {0.f, 0.f}, a1[2] = {0.f, 0.f};
        for (int kk = 0; kk < 128; ++kk) {
            const float4 c0 = cr0[kk], c1 = cr1[kk];
            #pragma unroll
            for (int g = 0; g < 2; ++g) {
                const float4 zv = z4[g * 128 + kk];
                a0[g] = dot4(c0, zv, a0[g]);
                a1[g] = dot4(c1, zv, a1[g]);
            }
        }
        #pragma unroll
        for (int g = 0; g < 2; ++g) {
            z2[g * 512 + t]       = a0[g];
            z2[g * 512 + t + 256] = a1[g];
        }
    }
    __syncthreads();

    float4 w[4][2];
    {
        const int cc = (4 * t) & 127;
        #pragma unroll
        for (int c = 0; c < 4; ++c) {
            w[c][0] = *(const float4*)(of2 + (cc + c) * 8);
            w[c][1] = *(const float4*)(of2 + (cc + c) * 8 + 4);
        }
    }

    float4* out4 = (float4*)out;
    #pragma unroll
    for (int g = 0; g < 2; ++g) {
        #pragma unroll
        for (int h = 0; h < 2; ++h) {
            const int id = t + 256 * h;
            const int o = id >> 6, Bq = (id >> 3) & 7, Cr = id & 7;
            float s = 0.f;
            #pragma unroll
            for (int A = 0; A < 8; ++A)
                s = fmaf(z2[g * 512 + A * 64 + Bq * 8 + Cr], s_of0T[A * 8 + o], s);
            t1[id] = s;
        }
        __syncthreads();
        #pragma unroll
        for (int h = 0; h < 2; ++h) {
            const int id = t + 256 * h;
            const int p = id >> 6, o = (id >> 3) & 7, Cr = id & 7;
            float s = 0.f;
            #pragma unroll
            for (int B0 = 0; B0 < 8; ++B0) {
                const int Bq = (B0 + o) & 7;
                s = fmaf(t1[o * 64 + Bq * 8 + Cr], s_of1T[Bq * 8 + p], s);
            }
            t2[id] = s;
        }
        __syncthreads();
        #pragma unroll
        for (int i = 0; i < 8; ++i) {
            const int m = (t >> 5) + 8 * i;
            const int o = m >> 3, p = m & 7;
            const float wv = s_winv[g * 64 + m];
            const int base = p * 64 + o * 8;
            const float4 v0 = *(const float4*)(t2 + base);
            const float4 v1 = *(const float4*)(t2 + base + 4);
            float4 r;
            r.x = dot4(v1, w[0][1], dot4(v0, w[0][0], acc[g][i].x));
            r.y = dot4(v1, w[1][1], dot4(v0, w[1][0], acc[g][i].y));
            r.z = dot4(v1, w[2][1], dot4(v0, w[2][0], acc[g][i].z));
            r.w = dot4(v1, w[3][1], dot4(v0, w[3][0], acc[g][i].w));
            r.x *= wv; r.y *= wv; r.z *= wv; r.w *= wv;
            out4[(size_t)(blk * 2 + g) * 2048 + t + 256 * i] = r;
        }
        __syncthreads();
    }
}

extern "C" void kernel_launch(void* const* d_in, const int* in_sizes, int n_in,
                              void* d_out, int out_size, void* d_ws, size_t ws_size,
                              hipStream_t stream) {
    const float* x    = (const float*)d_in[0];
    const float* core = (const float*)d_in[1];
    const float* of0  = (const float*)d_in[2];
    const float* of1  = (const float*)d_in[3];
    const float* of2  = (const float*)d_in[4];
    const float* if0  = (const float*)d_in[5];
    const float* if1  = (const float*)d_in[6];
    const float* if2  = (const float*)d_in[7];
    const int* mask   = (const int*)d_in[8];
    float* out = (float*)d_out;

    const size_t CORE_T_BYTES = (size_t)512 * 512 * 4;            // 1 MB
    const size_t XS_BYTES     = (size_t)2048 * 8192 * 2;          // 33.5 MB bf16

    if (d_ws && ws_size >= CORE_T_BYTES + XS_BYTES) {
        float* coreT    = (float*)d_ws;
        unsigned* xs_bf = (unsigned*)((char*)d_ws + CORE_T_BYTES);
        transpose_core<<<dim3(256), dim3(256), 0, stream>>>(core, coreT);
        noblock_main<<<dim3(512), dim3(512), 0, stream>>>(
            x, coreT, of0, of1, of2, if0, if1, if2, mask, xs_bf, out);
    } else {
        noblock_fused<<<dim3(1024), dim3(256), 0, stream>>>(
            x, core, of0, of1, of2, if0, if1, if2, mask, out);
    }
}